// Round 6
// baseline (137.620 us; speedup 1.0000x reference)
//
#include <hip/hip_runtime.h>

// Router: out[t] = x[t] @ W[split[t]] + b[split[t]]
// N=262144, D=128, E=8. fp32 in/out, bf16 MFMA.
// R6: persistent 1-block/CU pipeline. Double-buffered LDS x-tiles staged via
// global_load_lds; raw s_barrier + counted vmcnt(5) keeps next tile's loads
// in flight across barriers (T3/T4). All-expert B-fragments preloaded to
// registers (static-unrolled expert loop) so NO compiler global loads (and
// no compiler vmcnt(0) drains) exist in the steady-state loop.

typedef __bf16 bf16x8 __attribute__((ext_vector_type(8)));
typedef unsigned short u16x8 __attribute__((ext_vector_type(8)));
typedef float f32x4 __attribute__((ext_vector_type(4)));

typedef const __attribute__((address_space(1))) void* gptr_t;
typedef __attribute__((address_space(3))) void* lptr_t;

__device__ __forceinline__ unsigned short f2bf(float f) {
    unsigned u = __builtin_bit_cast(unsigned, f);
    u += 0x7FFFu + ((u >> 16) & 1u);   // RNE
    return (unsigned short)(u >> 16);
}

// Transpose + convert W[e][f][g] (f32) -> Wt[e][g][f] (bf16).
__global__ void k_wt(const float* __restrict__ W, unsigned short* __restrict__ Wt) {
    __shared__ float T[16][132];
    int e = blockIdx.x >> 3;
    int g0 = (blockIdx.x & 7) << 4;
    const float* We = W + e * 128 * 128;
    #pragma unroll
    for (int i = 0; i < 2; ++i) {
        int idx = i * 256 + threadIdx.x;
        int f = idx >> 2, q = idx & 3;
        float4 v = *(const float4*)(We + f * 128 + g0 + q * 4);
        T[q * 4 + 0][f] = v.x; T[q * 4 + 1][f] = v.y;
        T[q * 4 + 2][f] = v.z; T[q * 4 + 3][f] = v.w;
    }
    __syncthreads();
    int g = threadIdx.x >> 4, fc = threadIdx.x & 15;
    u16x8 o;
    #pragma unroll
    for (int j = 0; j < 8; ++j) o[j] = f2bf(T[g][fc * 8 + j]);
    *(u16x8*)(Wt + ((e * 128 + g0 + g) * 128 + fc * 8)) = o;
}

#define NTOK 64        // tokens per tile
#define GRID 256       // persistent blocks (1 per CU)

__global__ __launch_bounds__(512, 2) void k_fused(
    const float* __restrict__ x, const int* __restrict__ split,
    const float* __restrict__ bias, const unsigned short* __restrict__ Wt,
    float* __restrict__ out, int iters) {

    __shared__ float buf[2][NTOK * 128];    // 2 x 32 KB, global-side swizzled
    __shared__ int sL[2][NTOK];             // split staging
    __shared__ int trowL[2][NTOK];          // bucket slot -> local token row
    __shared__ int cntL[2][8], startL[2][8];

    const int tid = threadIdx.x;
    const int lane = tid & 63, w = tid >> 6;
    const int l15 = lane & 15, lq = lane >> 4;
    const int tbase = (int)blockIdx.x * iters;

    // ---- preload B fragments + bias for this wave's 16 cols, ALL experts ----
    bf16x8 bf_[8][4];
    float bv_[8];
    #pragma unroll
    for (int ee = 0; ee < 8; ++ee) {
        #pragma unroll
        for (int kk = 0; kk < 4; ++kk)
            bf_[ee][kk] = *(const bf16x8*)(Wt + ((ee * 128 + w * 16 + l15) * 128 + kk * 32 + lq * 8));
        bv_[ee] = bias[ee * 128 + w * 16 + l15];
    }

    // ---- staging helpers (global-side XOR swizzle, linear LDS dest) ----
    auto stage_x = [&](int tile, int p) {
        const char* gb = (const char*)(x + (long)tile * NTOK * 128);
        #pragma unroll
        for (int i = 0; i < 4; ++i) {
            int L = (w * 4 + i) * 64 + lane;         // 16B chunk id
            int row = L >> 5;
            int c = (L & 31) ^ (row & 31);           // source chunk (swizzle)
            __builtin_amdgcn_global_load_lds(
                (gptr_t)(const void*)(gb + row * 512 + c * 16),
                (lptr_t)(void*)((char*)&buf[p][0] + (w * 4 + i) * 1024),
                16, 0, 0);
        }
    };
    auto stage_split = [&](int tile, int p) {        // wave 3 only
        __builtin_amdgcn_global_load_lds(
            (gptr_t)(const void*)(split + tile * NTOK + lane),
            (lptr_t)(void*)&sL[p][0], 4, 0, 0);
    };
    // ballot bucketing of sL[p] -> trowL/cntL/startL[p]; wave 0 only
    auto ballot_meta = [&](int p) {
        int ev = sL[p][lane];
        unsigned long long below = (1ull << lane) - 1;
        int myrank = 0;
        #pragma unroll
        for (int ee = 0; ee < 8; ++ee) {
            unsigned long long m = __ballot(ev == ee);
            if (ev == ee) myrank = (int)__popcll(m & below);
            if (lane == ee) cntL[p][lane] = (int)__popcll(m);
        }
        if (lane < 8) {
            int s = 0;
            #pragma unroll
            for (int j = 0; j < 8; ++j) s += (j < lane) ? cntL[p][j] : 0;
            startL[p][lane] = s;
        }
        trowL[p][startL[p][ev] + myrank] = lane;
    };

    // ---- prologue: stage split(0),split(1),x(0); drain; meta(0) ----
    if (w == 3) { stage_split(tbase, 0); stage_split(tbase + 1 < tbase + iters ? tbase + 1 : tbase, 1); }
    stage_x(tbase, 0);
    asm volatile("s_waitcnt vmcnt(0)" ::: "memory");
    __builtin_amdgcn_s_barrier();
    if (w == 0) ballot_meta(0);

    // ---- steady state ----
    for (int t = 0; t < iters; ++t) {
        const int p = t & 1;
        __builtin_amdgcn_s_barrier();                       // A: buf[(t+1)&1] free
        int t1 = (t + 1 < iters) ? t + 1 : iters - 1;
        int t2 = (t + 2 < iters) ? t + 2 : iters - 1;
        if (w == 3) stage_split(tbase + t2, p);             // (t+2)&1 == p
        stage_x(tbase + t1, p ^ 1);
        asm volatile("s_waitcnt vmcnt(5)" ::: "memory");    // x(t)+split(t+1) done;
        __builtin_amdgcn_s_barrier();                       // B: visible to all
        if (w == 0) ballot_meta(p ^ 1);                     // meta for tile t+1

        // ---- compute tile t from buf[p] ----
        const long t0 = (long)(tbase + t) * NTOK;
        #pragma unroll
        for (int ee = 0; ee < 8; ++ee) {
            int cnt = cntL[p][ee];
            int st = startL[p][ee];
            for (int k2 = 0; k2 * 16 < cnt; ++k2) {
                int rb = st + k2 * 16;
                int rem = cnt - k2 * 16;
                int lim = rem < 16 ? rem : 16;
                int sr = rb + l15; sr = sr < NTOK ? sr : NTOK - 1;
                int srow = trowL[p][sr];
                f32x4 acc = {0.f, 0.f, 0.f, 0.f};
                #pragma unroll
                for (int kk = 0; kk < 4; ++kk) {
                    int c0 = kk * 8 + lq * 2;
                    float4 va = *(const float4*)&buf[p][srow * 128 + ((c0 ^ (srow & 31)) << 2)];
                    float4 vb = *(const float4*)&buf[p][srow * 128 + (((c0 + 1) ^ (srow & 31)) << 2)];
                    u16x8 u;
                    u[0] = f2bf(va.x); u[1] = f2bf(va.y); u[2] = f2bf(va.z); u[3] = f2bf(va.w);
                    u[4] = f2bf(vb.x); u[5] = f2bf(vb.y); u[6] = f2bf(vb.z); u[7] = f2bf(vb.w);
                    acc = __builtin_amdgcn_mfma_f32_16x16x32_bf16(
                        __builtin_bit_cast(bf16x8, u), bf_[ee][kk], acc, 0, 0, 0);
                }
                #pragma unroll
                for (int r = 0; r < 4; ++r) {
                    int ri = lq * 4 + r;
                    if (ri < lim)
                        out[(t0 + trowL[p][rb + ri]) * 128 + w * 16 + l15] = acc[r] + bv_[ee];
                }
            }
        }
    }
}

extern "C" void kernel_launch(void* const* d_in, const int* in_sizes, int n_in,
                              void* d_out, int out_size, void* d_ws, size_t ws_size,
                              hipStream_t stream) {
    const float* x     = (const float*)d_in[0];
    const int*   split = (const int*)d_in[1];
    const float* W     = (const float*)d_in[2];
    const float* bias  = (const float*)d_in[3];
    float* out = (float*)d_out;

    int n = in_sizes[1];                      // 262144
    unsigned short* Wt = (unsigned short*)d_ws;   // 8*128*128 bf16 = 256 KB

    int ntiles = n / NTOK;                    // 4096
    int iters = ntiles / GRID;                // 16

    k_wt<<<64, 256, 0, stream>>>(W, Wt);
    k_fused<<<GRID, 512, 0, stream>>>(x, split, bias, Wt, out, iters);
}